// Round 1
// baseline (1878.489 us; speedup 1.0000x reference)
//
#include <hip/hip_runtime.h>
#include <cstdint>
#include <cstddef>

#define BB 32
#define LL 2048
#define DD 64
#define NKB 16   // k-blocks per row in k_scores (LL/128)

// masked scores get a huge negative finite value: expf(s - m) == 0 exactly,
// identical post-softmax to the reference's -inf / -1e32 fills.
#define BIG_NEG (-3.0e38f)

// ---------------------------------------------------------------------------
// K1: raw masked scores  S[b][q][k] = (q·k)/8, masked -> BIG_NEG
// tile 128(q) x 128(k), 256 threads, 8x8 micro, D chunked by 32 in LDS.
// LDS layout: transposed [d][col'] with rotation swizzle col' = col + 4*(d>>2)
//   col stride 156 (156%32==28): staging scatter writes are exactly 2-way
//   (free), B-side reads use cols {4tx, 64+4tx} -> 2-way (free).
// Epilogue additionally emits per-(row, k-block) partial softmax stats:
//   pm = max over 128 cols, pl = sum exp(s - pm).
// ---------------------------------------------------------------------------
__global__ __launch_bounds__(256) void k_scores(
    const float* __restrict__ q, const float* __restrict__ kmat,
    const int* __restrict__ diag, const int* __restrict__ mask,
    float* __restrict__ attn, float* __restrict__ pm, float* __restrict__ pl)
{
    __shared__ __align__(16) float sQT[32][156];  // [d][col'], col' <= 155
    __shared__ __align__(16) float sKT[32][156];

    const int b  = blockIdx.z;
    const int q0 = blockIdx.y * 128;
    const int k0 = blockIdx.x * 128;
    const int t  = threadIdx.x;
    const int tx = t & 15;        // col group
    const int ty = t >> 4;        // row group: rows 8*ty .. 8*ty+7
    const int tyb = ty * 8;
    const int txb = tx * 4;

    const float* qb = q    + ((size_t)b * LL + q0) * DD;
    const float* kb = kmat + ((size_t)b * LL + k0) * DD;

    float acc[8][8];
    #pragma unroll
    for (int i = 0; i < 8; ++i)
        #pragma unroll
        for (int j = 0; j < 8; ++j) acc[i][j] = 0.0f;

    for (int dc = 0; dc < DD; dc += 32) {
        // stage 128 rows x 32 d of Q and K, transposed + rotation-swizzled
        #pragma unroll
        for (int i = 0; i < 4; ++i) {
            int lin = t + 256 * i;        // 0..1023 float4 slots
            int row = lin >> 3;           // 0..127
            int dv  = lin & 7;            // d4 block 0..7
            int cc  = row + dv * 4;       // rotation swizzle, <= 155
            float4 a = *(const float4*)(qb + (size_t)row * DD + dc + dv * 4);
            sQT[dv * 4 + 0][cc] = a.x;
            sQT[dv * 4 + 1][cc] = a.y;
            sQT[dv * 4 + 2][cc] = a.z;
            sQT[dv * 4 + 3][cc] = a.w;
            float4 c4 = *(const float4*)(kb + (size_t)row * DD + dc + dv * 4);
            sKT[dv * 4 + 0][cc] = c4.x;
            sKT[dv * 4 + 1][cc] = c4.y;
            sKT[dv * 4 + 2][cc] = c4.z;
            sKT[dv * 4 + 3][cc] = c4.w;
        }
        __syncthreads();

        #pragma unroll
        for (int d = 0; d < 32; ++d) {
            const int rot = d & 28;       // 4*(d>>2), compile-time per unroll
            float4 a0 = *(const float4*)&sQT[d][tyb + rot];
            float4 a1 = *(const float4*)&sQT[d][tyb + 4 + rot];
            float4 b0 = *(const float4*)&sKT[d][txb + rot];
            float4 b1 = *(const float4*)&sKT[d][txb + 64 + rot];
            float aa[8] = {a0.x, a0.y, a0.z, a0.w, a1.x, a1.y, a1.z, a1.w};
            float bb[8] = {b0.x, b0.y, b0.z, b0.w, b1.x, b1.y, b1.z, b1.w};
            #pragma unroll
            for (int ri = 0; ri < 8; ++ri)
                #pragma unroll
                for (int ci = 0; ci < 8; ++ci)
                    acc[ri][ci] = fmaf(aa[ri], bb[ci], acc[ri][ci]);
        }
        __syncthreads();
    }

    // epilogue: scale by 1/8, apply masks, write raw scores, emit stats.
    // thread's cols: {k0+4tx+j} and {k0+64+4tx+j}, j=0..3
    #pragma unroll
    for (int ri = 0; ri < 8; ++ri) {
        int qq = q0 + tyb + ri;
        size_t rb    = ((size_t)b * LL + qq) * LL + k0;
        size_t base0 = rb + txb;
        size_t base1 = rb + txb + 64;
        int4 dm0 = *(const int4*)(diag + base0);
        int4 dm1 = *(const int4*)(diag + base1);
        int4 mk0 = *(const int4*)(mask + base0);
        int4 mk1 = *(const int4*)(mask + base1);
        int dmv[8] = {dm0.x, dm0.y, dm0.z, dm0.w, dm1.x, dm1.y, dm1.z, dm1.w};
        int mkv[8] = {mk0.x, mk0.y, mk0.z, mk0.w, mk1.x, mk1.y, mk1.z, mk1.w};
        float o[8];
        #pragma unroll
        for (int ci = 0; ci < 8; ++ci) {
            float s = acc[ri][ci] * 0.125f;
            o[ci] = (dmv[ci] == 0 || mkv[ci] != 0) ? BIG_NEG : s;
        }
        *(float4*)(attn + base0) = make_float4(o[0], o[1], o[2], o[3]);
        *(float4*)(attn + base1) = make_float4(o[4], o[5], o[6], o[7]);

        if (pm != nullptr) {
            // row max over this block's 128 cols (16 tx lanes x 8 cols)
            float rm = fmaxf(fmaxf(fmaxf(o[0], o[1]), fmaxf(o[2], o[3])),
                             fmaxf(fmaxf(o[4], o[5]), fmaxf(o[6], o[7])));
            #pragma unroll
            for (int off = 8; off >= 1; off >>= 1)
                rm = fmaxf(rm, __shfl_xor(rm, off, 64));
            float rs = 0.0f;
            #pragma unroll
            for (int ci = 0; ci < 8; ++ci) rs += __expf(o[ci] - rm);
            #pragma unroll
            for (int off = 8; off >= 1; off >>= 1)
                rs += __shfl_xor(rs, off, 64);
            if (tx == 0) {
                size_t pidx = ((size_t)b * LL + qq) * NKB + blockIdx.x;
                pm[pidx] = rm;
                pl[pidx] = rs;
            }
        }
    }
}

// ---------------------------------------------------------------------------
// K2: combine 16 per-block partials per row -> stats[row] = (m, 1/l)
// ---------------------------------------------------------------------------
__global__ __launch_bounds__(256) void k_reduce(
    const float* __restrict__ pm, const float* __restrict__ pl,
    float2* __restrict__ stats)
{
    int row = blockIdx.x * 256 + threadIdx.x;   // 0 .. B*L-1
    const float4* m4 = (const float4*)(pm + (size_t)row * NKB);
    const float4* l4 = (const float4*)(pl + (size_t)row * NKB);
    float4 m0 = m4[0], m1 = m4[1], m2 = m4[2], m3 = m4[3];
    float4 l0 = l4[0], l1 = l4[1], l2 = l4[2], l3 = l4[3];
    float m = fmaxf(fmaxf(fmaxf(fmaxf(m0.x, m0.y), fmaxf(m0.z, m0.w)),
                          fmaxf(fmaxf(m1.x, m1.y), fmaxf(m1.z, m1.w))),
                    fmaxf(fmaxf(fmaxf(m2.x, m2.y), fmaxf(m2.z, m2.w)),
                          fmaxf(fmaxf(m3.x, m3.y), fmaxf(m3.z, m3.w))));
    float l = l0.x * __expf(m0.x - m) + l0.y * __expf(m0.y - m)
            + l0.z * __expf(m0.z - m) + l0.w * __expf(m0.w - m)
            + l1.x * __expf(m1.x - m) + l1.y * __expf(m1.y - m)
            + l1.z * __expf(m1.z - m) + l1.w * __expf(m1.w - m)
            + l2.x * __expf(m2.x - m) + l2.y * __expf(m2.y - m)
            + l2.z * __expf(m2.z - m) + l2.w * __expf(m2.w - m)
            + l3.x * __expf(m3.x - m) + l3.y * __expf(m3.y - m)
            + l3.z * __expf(m3.z - m) + l3.w * __expf(m3.w - m);
    stats[row] = make_float2(m, 1.0f / l);
}

// ---------------------------------------------------------------------------
// K2b (fallback, tiny ws): per-row stats directly from S (no partials buffer)
// ---------------------------------------------------------------------------
__global__ __launch_bounds__(256) void k_rowstats(
    const float* __restrict__ attn, float2* __restrict__ stats)
{
    __shared__ float redm[4];
    __shared__ float reds[4];
    const float* p = attn + (size_t)blockIdx.x * LL;
    const int t = threadIdx.x;
    const int wave = t >> 6, lane = t & 63;

    float4 x0 = ((const float4*)p)[t];
    float4 x1 = ((const float4*)p)[t + 256];

    float m = fmaxf(fmaxf(fmaxf(x0.x, x0.y), fmaxf(x0.z, x0.w)),
                    fmaxf(fmaxf(x1.x, x1.y), fmaxf(x1.z, x1.w)));
    #pragma unroll
    for (int off = 32; off >= 1; off >>= 1)
        m = fmaxf(m, __shfl_xor(m, off, 64));
    if (lane == 0) redm[wave] = m;
    __syncthreads();
    m = fmaxf(fmaxf(redm[0], redm[1]), fmaxf(redm[2], redm[3]));

    float s = __expf(x0.x - m) + __expf(x0.y - m)
            + __expf(x0.z - m) + __expf(x0.w - m)
            + __expf(x1.x - m) + __expf(x1.y - m)
            + __expf(x1.z - m) + __expf(x1.w - m);
    #pragma unroll
    for (int off = 32; off >= 1; off >>= 1)
        s += __shfl_xor(s, off, 64);
    if (lane == 0) reds[wave] = s;
    __syncthreads();
    s = (reds[0] + reds[1]) + (reds[2] + reds[3]);

    if (t == 0) stats[blockIdx.x] = make_float2(m, 1.0f / s);
}

// ---------------------------------------------------------------------------
// Tier-C fallback: original in-place row softmax (only if no workspace)
// ---------------------------------------------------------------------------
__global__ __launch_bounds__(256) void k_softmax(float* __restrict__ attn)
{
    __shared__ float redm[4];
    __shared__ float reds[4];
    float* p = attn + (size_t)blockIdx.x * LL;
    const int t = threadIdx.x;
    const int wave = t >> 6, lane = t & 63;

    float4 x0 = ((const float4*)p)[t];
    float4 x1 = ((const float4*)p)[t + 256];

    float m = fmaxf(fmaxf(fmaxf(x0.x, x0.y), fmaxf(x0.z, x0.w)),
                    fmaxf(fmaxf(x1.x, x1.y), fmaxf(x1.z, x1.w)));
    #pragma unroll
    for (int off = 32; off >= 1; off >>= 1)
        m = fmaxf(m, __shfl_xor(m, off, 64));
    if (lane == 0) redm[wave] = m;
    __syncthreads();
    m = fmaxf(fmaxf(redm[0], redm[1]), fmaxf(redm[2], redm[3]));

    x0.x = expf(x0.x - m); x0.y = expf(x0.y - m);
    x0.z = expf(x0.z - m); x0.w = expf(x0.w - m);
    x1.x = expf(x1.x - m); x1.y = expf(x1.y - m);
    x1.z = expf(x1.z - m); x1.w = expf(x1.w - m);

    float s = (x0.x + x0.y + x0.z + x0.w) + (x1.x + x1.y + x1.z + x1.w);
    #pragma unroll
    for (int off = 32; off >= 1; off >>= 1)
        s += __shfl_xor(s, off, 64);
    if (lane == 0) reds[wave] = s;
    __syncthreads();
    s = (reds[0] + reds[1]) + (reds[2] + reds[3]);

    float inv = 1.0f / s;
    x0.x *= inv; x0.y *= inv; x0.z *= inv; x0.w *= inv;
    x1.x *= inv; x1.y *= inv; x1.z *= inv; x1.w *= inv;
    ((float4*)p)[t]       = x0;
    ((float4*)p)[t + 256] = x1;
}

// ---------------------------------------------------------------------------
// K3: fused softmax-apply + P write-back + PV.
//   reads raw S tile, computes p = exp(s - m) * (1/l), stores P to attn
//   (required output) and accumulates out = P @ V.
// If stats == nullptr, attn already holds P (Tier-C path): plain PV.
// sPT uses rotation swizzle col' = row + 4*(k>>2), stride 188 (188%32==28):
//   scatter writes exactly 2-way (free).
// ---------------------------------------------------------------------------
__global__ __launch_bounds__(256) void k_pv_softmax(
    float* __restrict__ attn, const float* __restrict__ v,
    const float2* __restrict__ stats, float* __restrict__ out)
{
    __shared__ __align__(16) float sPT[64][188];  // [k][col'], col' <= 187
    __shared__ __align__(16) float sV[64][68];    // [k][d]
    __shared__ float sM[128];
    __shared__ float sIL[128];

    const int b  = blockIdx.y;
    const int q0 = blockIdx.x * 128;
    const int t  = threadIdx.x;
    const int tx = t & 15;        // cols 4*tx .. 4*tx+3
    const int ty = t >> 4;        // rows 8*ty .. 8*ty+7
    const int tyb = ty * 8;
    const int txb = tx * 4;

    float* pb = attn + ((size_t)b * LL + q0) * LL;
    const float* vb = v + (size_t)b * LL * DD;

    if (stats != nullptr && t < 128) {
        float2 st = stats[(size_t)b * LL + q0 + t];
        sM[t]  = st.x;
        sIL[t] = st.y;
    }
    __syncthreads();

    float acc[8][4];
    #pragma unroll
    for (int i = 0; i < 8; ++i)
        #pragma unroll
        for (int j = 0; j < 4; ++j) acc[i][j] = 0.0f;

    for (int k0 = 0; k0 < LL; k0 += 64) {
        // stage P tile 128 x 64: load raw S, apply softmax, write P back,
        // scatter transposed+swizzled into LDS
        #pragma unroll
        for (int i = 0; i < 8; ++i) {
            int lin = t + 256 * i;   // 0..2047 float4 slots
            int row = lin >> 4;      // 0..127
            int kv  = lin & 15;
            float* src = pb + (size_t)row * LL + k0 + kv * 4;
            float4 a = *(const float4*)src;
            if (stats != nullptr) {
                float m  = sM[row];
                float il = sIL[row];
                a.x = __expf(a.x - m) * il;
                a.y = __expf(a.y - m) * il;
                a.z = __expf(a.z - m) * il;
                a.w = __expf(a.w - m) * il;
                *(float4*)src = a;   // P is a required output
            }
            int cc = row + kv * 4;   // rotation swizzle, <= 187
            sPT[kv * 4 + 0][cc] = a.x;
            sPT[kv * 4 + 1][cc] = a.y;
            sPT[kv * 4 + 2][cc] = a.z;
            sPT[kv * 4 + 3][cc] = a.w;
        }
        // stage V tile 64 x 64, natural
        #pragma unroll
        for (int i = 0; i < 4; ++i) {
            int lin = t + 256 * i;   // 0..1023
            int row = lin >> 4;      // 0..63
            int dv  = lin & 15;
            *(float4*)&sV[row][dv * 4] =
                *(const float4*)(vb + (size_t)(k0 + row) * DD + dv * 4);
        }
        __syncthreads();

        #pragma unroll
        for (int kk = 0; kk < 64; ++kk) {
            const int rot = kk & 60;   // 4*(kk>>2)
            float4 a0 = *(const float4*)&sPT[kk][tyb + rot];
            float4 a1 = *(const float4*)&sPT[kk][tyb + 4 + rot];
            float4 b0 = *(const float4*)&sV[kk][txb];
            float aa[8] = {a0.x, a0.y, a0.z, a0.w, a1.x, a1.y, a1.z, a1.w};
            float bb[4] = {b0.x, b0.y, b0.z, b0.w};
            #pragma unroll
            for (int ri = 0; ri < 8; ++ri)
                #pragma unroll
                for (int ci = 0; ci < 4; ++ci)
                    acc[ri][ci] = fmaf(aa[ri], bb[ci], acc[ri][ci]);
        }
        __syncthreads();
    }

    #pragma unroll
    for (int ri = 0; ri < 8; ++ri) {
        float4 o = make_float4(acc[ri][0], acc[ri][1], acc[ri][2], acc[ri][3]);
        *(float4*)(out + ((size_t)b * LL + q0 + tyb + ri) * DD + txb) = o;
    }
}

// ---------------------------------------------------------------------------
extern "C" void kernel_launch(void* const* d_in, const int* in_sizes, int n_in,
                              void* d_out, int out_size, void* d_ws, size_t ws_size,
                              hipStream_t stream)
{
    const float* q    = (const float*)d_in[0];
    const float* k    = (const float*)d_in[1];
    const float* v    = (const float*)d_in[2];
    const int*   diag = (const int*)d_in[3];
    const int*   mask = (const int*)d_in[4];   // ASSUMPTION: bool uploaded as int32

    float* out  = (float*)d_out;                       // [B, L, D]
    float* attn = out + (size_t)BB * LL * DD;          // [B, L, L]

    const size_t ROWS = (size_t)BB * LL;               // 65536
    const size_t PART_FLOATS = ROWS * NKB;             // per partial array
    const size_t needA = PART_FLOATS * 4 * 2 + ROWS * 8;   // pm+pl+stats ~8.5 MB
    const size_t needB = ROWS * 8;                          // stats only  512 KB

    if (d_ws != nullptr && ws_size >= needA) {
        // Tier A: fused-stats pipeline
        float*  pm    = (float*)d_ws;
        float*  pl    = pm + PART_FLOATS;
        float2* stats = (float2*)(pl + PART_FLOATS);
        k_scores    <<<dim3(LL / 128, LL / 128, BB), 256, 0, stream>>>(
                        q, k, diag, mask, attn, pm, pl);
        k_reduce    <<<dim3((int)(ROWS / 256)),       256, 0, stream>>>(pm, pl, stats);
        k_pv_softmax<<<dim3(LL / 128, BB),            256, 0, stream>>>(attn, v, stats, out);
    } else if (d_ws != nullptr && ws_size >= needB) {
        // Tier B: stats recomputed from S (one extra 512 MB read)
        float2* stats = (float2*)d_ws;
        k_scores    <<<dim3(LL / 128, LL / 128, BB), 256, 0, stream>>>(
                        q, k, diag, mask, attn, nullptr, nullptr);
        k_rowstats  <<<dim3(BB * LL),                 256, 0, stream>>>(attn, stats);
        k_pv_softmax<<<dim3(LL / 128, BB),            256, 0, stream>>>(attn, v, stats, out);
    } else {
        // Tier C: original 3-pass pipeline (no workspace available)
        k_scores    <<<dim3(LL / 128, LL / 128, BB), 256, 0, stream>>>(
                        q, k, diag, mask, attn, nullptr, nullptr);
        k_softmax   <<<dim3(BB * LL),                 256, 0, stream>>>(attn);
        k_pv_softmax<<<dim3(LL / 128, BB),            256, 0, stream>>>(attn, v, nullptr, out);
    }
}